// Round 12
// baseline (165.957 us; speedup 1.0000x reference)
//
#include <hip/hip_runtime.h>
#include <math.h>

// Closed-form pipeline with Hermitian (real-output) symmetry:
//   k13: blocks [0,4096) row-FFT of x (pack-2, cols 0..64, wave-local
//        barrier-free stages); blocks beyond: psf row FFTs -> FBtmp
//   k2:  column FFT of Fx (in-place wave-owned radix-4), cols 0..64
//   k6 fused: on-the-fly column DFT of FBtmp -> 4 FBh rows; M; FX;
//             radix-4 row IFFT (stage1+stage4 in regs); Hermitian fold
//   k7:  pure 128-pt C2R column IFFT of Zf (in-place, 32 cols x 512 thr)
// R9: wave-owns-row/col FFT stages need NO barriers (in-order DS in wave).
// R10: Fx 2D-Hermitian halving. R11: FBh never materialized (25-tap dots).
// R12: LDS overlays -> 19.5 KB. R13: min-waves below reg floor (spill!).
// R14: stage1/stage4 in regs, PHI16. R15: parity-split FMA DFT (70->51.6).
// R16: k13 barrier-free; per-wave Tt; folded normalization (k6 = 51.1us).
// R17: in-place k2/k7 (LDS halved, occupancy 100%); Fx-hoist REGRESSED
//   (VGPR 40->44, occ 51->42, k6 +2.7us) -> reverted in R18.
// R18: (a) k6 reverted to R16 form; (b) in-place col FFT internal barriers
//   deleted (cols are wave-owned; reads precede writes in program order);
//   (c) k7 widened to 32 cols x 512 threads, pad 131 (2-way transpose
//   conflicts, 128-256B contiguous global runs).

static __device__ __forceinline__ float2 cmul(float2 a, float2 b) {
    return make_float2(a.x * b.x - a.y * b.y, a.x * b.y + a.y * b.x);
}
static __device__ __forceinline__ float2 cadd(float2 a, float2 b) {
    return make_float2(a.x + b.x, a.y + b.y);
}
static __device__ __forceinline__ float2 csub(float2 a, float2 b) {
    return make_float2(a.x - b.x, a.y - b.y);
}
static __device__ __forceinline__ float2 conjf2(float2 a) {
    return make_float2(a.x, -a.y);
}
static __device__ __forceinline__ int PHI16(int i) { return i + ((i >> 4) << 1); }

// ---- in-place wave-owned mixed radix-4/2 128-pt column FFT (R17/R18) ----
// buf[NCOL][131]; each wave owns 4 cols (16 lanes/col). All 8 reads of a
// stage precede its 8 writes in program order; DS is in-order within a
// wave and cols are wave-disjoint -> NO barriers anywhere.
template <int SIGN, int NCOL>
static __device__ __forceinline__ void fft4_cols_inplace(float2 (&buf)[NCOL][131],
                                                         const float2* __restrict__ tw) {
    const int lane = threadIdx.x & 63;
    const int wv = threadIdx.x >> 6;
    const int col = wv * 4 + (lane >> 4);
    const int r = lane & 15;
    int m = 1;
#pragma unroll
    for (int st = 0; st < 3; ++st) {
        float2 o0[2], o1[2], o2[2], o3[2];
        int ob_[2];
#pragma unroll
        for (int b = 0; b < 2; ++b) {
            const int bq = r + 16 * b;
            const int k = bq & (m - 1);
            const int jm = bq - k;
            float2 a0 = buf[col][bq];
            float2 a1 = buf[col][bq + 32];
            float2 a2 = buf[col][bq + 64];
            float2 a3 = buf[col][bq + 96];
            float2 s02 = cadd(a0, a2), d02 = csub(a0, a2);
            float2 s13 = cadd(a1, a3), d13 = csub(a1, a3);
            o0[b] = cadd(s02, s13);
            float2 b2 = csub(s02, s13);
            float2 b1 = make_float2(d02.x - (float)SIGN * d13.y,
                                    d02.y + (float)SIGN * d13.x);
            float2 b3 = make_float2(d02.x + (float)SIGN * d13.y,
                                    d02.y - (float)SIGN * d13.x);
            o1[b] = cmul(tw[jm], b1);
            o2[b] = cmul(tw[2 * jm], b2);
            o3[b] = cmul(tw[3 * jm], b3);
            ob_[b] = 4 * jm + k;
        }
#pragma unroll
        for (int b = 0; b < 2; ++b) {
            const int o = ob_[b];
            buf[col][o] = o0[b];
            buf[col][o + m] = o1[b];
            buf[col][o + 2 * m] = o2[b];
            buf[col][o + 3 * m] = o3[b];
        }
        m <<= 2;
    }
#pragma unroll
    for (int b = 0; b < 4; ++b) {  // radix-2 tail, m=64, j=0, thread-local
        const int bt = r + 16 * b;
        float2 a = buf[col][bt];
        float2 bb = buf[col][bt + 64];
        buf[col][bt] = cadd(a, bb);
        buf[col][bt + 64] = csub(a, bb);
    }
}

// K13: merged k1 (x row FFT) + k3 (psf row FFT), both wave-per-row,
// barrier-free stages (R16). One barrier total (tw table publish).
__global__ __launch_bounds__(256) void k13(const float* __restrict__ x,
                                           const float* __restrict__ kin,
                                           float2* __restrict__ Fx,
                                           float2* __restrict__ FBtmp) {
    __shared__ __align__(16) float2 pool[2176];  // k1: 1024+64; k3: 2048+128
    const int tid = threadIdx.x;
    const int rs = tid >> 6;
    const int lane = tid & 63;
    if (blockIdx.x < 4096) {
        float2* tw = pool + 1024;  // 64 entries, e^{-i pi k/64}
        for (int i = tid; i < 64; i += 256) {
            float s, c;
            __sincosf(-(float)M_PI * (float)i / 64.f, &s, &c);
            tw[i] = make_float2(c, s);
        }
        const int gpair = blockIdx.x * 4 + rs;  // img*64 + pr
        const float* r0 = x + (size_t)gpair * 256;
        const float* r1 = r0 + 128;
        const float2 a0 = ((const float2*)r0)[lane];
        const float2 a1 = ((const float2*)r1)[lane];
        float2* R = pool + rs * 128;            // cur=0 slot for this wave
        R[2 * lane] = make_float2(a0.x, a1.x);
        R[2 * lane + 1] = make_float2(a0.y, a1.y);
        __syncthreads();  // tw visible (row data is wave-local already)
        int cur = 0, m = 1;
        for (int l = 64; l >= 1; l >>= 1) {   // 7 stages, barrier-free
            float2* Bc = pool + cur * 512 + rs * 128;
            float2* Bn = pool + (cur ^ 1) * 512 + rs * 128;
            const int k = lane & (m - 1);
            const float2 w = tw[lane - k];
            float2 a = Bc[lane];
            float2 b = Bc[lane + 64];
            float2 d = csub(a, b);
            const int o = 2 * lane - k;
            Bn[o] = cadd(a, b);
            Bn[o + m] = cmul(w, d);
            cur ^= 1;
            m <<= 1;
        }
        float2* Bc = pool + cur * 512 + rs * 128;
        float2* d0 = Fx + (size_t)gpair * 256;
        float2* d1 = d0 + 128;
        for (int h = 0; h < 2; ++h) {
            int tt = lane + h * 64;
            if (tt > 64) continue;  // Hermitian: cols 65..127 rebuilt in k6
            float2 Zt = Bc[tt];
            float2 Zm = Bc[(128 - tt) & 127];
            d0[tt] = make_float2(0.5f * (Zt.x + Zm.x), 0.5f * (Zt.y - Zm.y));
            float ax = Zt.x - Zm.x, ay = Zt.y + Zm.y;
            d1[tt] = make_float2(0.5f * ay, -0.5f * ax);
        }
    } else {
        float2* tw = pool + 2048;  // 128 entries, e^{-i pi k/128}
        for (int i = tid; i < 128; i += 256) {
            float s, c;
            __sincosf(-(float)M_PI * (float)i / 128.f, &s, &c);
            tw[i] = make_float2(c, s);
        }
        const int b3 = blockIdx.x - 4096;
        const int img = b3 / 7;
        const int sub = b3 % 7;
        int lr = sub * 4 + rs;
        const bool live = (lr < 25);
        if (!live) lr = 24;  // dead wave computes garbage, no store
        const float* krow = kin + img * 625 + lr * 25;
        float2* R = pool + rs * 256;
#pragma unroll
        for (int h = 0; h < 4; ++h) {
            int v = lane + h * 64;
            int pc = (v + 12) & 255;
            R[v] = make_float2(pc < 25 ? krow[pc] : 0.f, 0.f);
        }
        __syncthreads();  // tw visible
        int cur = 0, m = 1;
        for (int l = 128; l >= 1; l >>= 1) {  // 8 stages, barrier-free
            float2* Bc = pool + cur * 1024 + rs * 256;
            float2* Bn = pool + (cur ^ 1) * 1024 + rs * 256;
#pragma unroll
            for (int b = 0; b < 2; ++b) {
                const int bt = lane + 64 * b;
                const int k = bt & (m - 1);
                const float2 w = tw[bt - k];
                float2 a = Bc[bt];
                float2 bb = Bc[bt + 128];
                float2 d = csub(a, bb);
                const int o = 2 * bt - k;
                Bn[o] = cadd(a, bb);
                Bn[o + m] = cmul(w, d);
            }
            cur ^= 1;
            m <<= 1;
        }
        if (live) {
            float2* Bc = pool + cur * 1024 + rs * 256;
            float2* dst = FBtmp + (size_t)img * 6400 + lr * 256;
#pragma unroll
            for (int h = 0; h < 4; ++h) {
                int v = lane + h * 64;
                dst[v] = Bc[v];
            }
        }
    }
}

// K2: column FFT of Fx, in place, cols 0..64 only -> 5 tiles of 16.
__global__ __launch_bounds__(256) void k2_fft_cols_x(float2* __restrict__ Fx) {
    __shared__ float2 buf[16][131];
    __shared__ float2 tw[96];
    const int tid = threadIdx.x;
    const int img = blockIdx.x / 5;
    const int c0 = (blockIdx.x % 5) * 16;
    for (int i = tid; i < 96; i += 256) {
        float s, c;
        __sincosf(-(float)M_PI * (float)i / 64.f, &s, &c);
        tw[i] = make_float2(c, s);
    }
    float2* base = Fx + (size_t)img * 16384 + c0;
    for (int it = 0; it < 8; ++it) {
        int idx = it * 256 + tid;
        int rr = idx >> 4, cc = idx & 15;
        buf[cc][rr] = base[rr * 128 + cc];
    }
    __syncthreads();
    fft4_cols_inplace<-1, 16>(buf, tw);
    __syncthreads();
    for (int it = 0; it < 8; ++it) {
        int idx = it * 256 + tid;
        int rr = idx >> 4, cc = idx & 15;
        base[rr * 128 + cc] = buf[cc][rr];
    }
}

// K6: fused column-DFT + M + FX build + radix-4 row IFFT + Hermitian fold.
// Block = (img, p-pair {pa=2b, pb=2b+1}); wave rs owns one of 4 rows.
// R18: reverted to R16 form (Fx loads post-B1; VGPR 40, occ ~51%).
__global__ __launch_bounds__(256, 4) void k6_fused(const float2* __restrict__ FBtmp,
                                                   const float2* __restrict__ Fx,
                                                   const float* __restrict__ alpha,
                                                   float2* __restrict__ Zf) {
    __shared__ __align__(16) float2 sm_buf0[4 * 288];  // per-wave Tt; FFT buf A
    __shared__ __align__(16) float2 sm_buf1[4 * 288];  // stage overlay; FFT buf B
    __shared__ float2 tw[192];                         // e^{+i pi k/128}, k<192
    float2* stageF = sm_buf1;            // [4][256] flat
    const int tid = threadIdx.x;
    const int rs = tid >> 6;             // row slot = wave id
    const int q = tid & 63;
    const int img = blockIdx.x / 33;
    const int bq = blockIdx.x % 33;
    const int pa = 2 * bq;
    const int pb = (pa + 1 < 65) ? (pa + 1) : 64;   // last block: pb==pa==64

    const float2* src = FBtmp + (size_t)img * 6400 + tid;
    float2 S[25];
#pragma unroll
    for (int p = 0; p < 25; ++p) S[p] = src[p * 256];

    for (int i = tid; i < 192; i += 256) {
        float s, c;
        __sincosf((float)M_PI * (float)i / 128.f, &s, &c);
        tw[i] = make_float2(c, s);
    }
    // Per-wave DFT twiddles (R16): wave rs fills its OWN 50-entry copy.
    float2* Ttw = sm_buf0 + rs * 288;
    if (q < 50) {
        const int which = q >= 25;
        const int pp = which ? (q - 25) : q;
        const int uu = which ? pb : pa;
        const float k2pi = -2.f * (float)M_PI / 256.f;
        float s, c;
        __sincosf(k2pi * (float)((uu * (pp + 244)) & 255), &s, &c);
        Ttw[q] = make_float2(c, s);
    }

    // R15: parity-split FMA DFT. Per tap: 8 FMAs. Mirror recombination once.
    {
        float AExx = 0.f, AEyy = 0.f, AExy = 0.f, AEyx = 0.f;
        float AOxx = 0.f, AOyy = 0.f, AOxy = 0.f, AOyx = 0.f;
        float BExx = 0.f, BEyy = 0.f, BExy = 0.f, BEyx = 0.f;
        float BOxx = 0.f, BOyy = 0.f, BOxy = 0.f, BOyx = 0.f;
#pragma unroll
        for (int pp = 0; pp < 25; ++pp) {
            const float2 s = S[pp];
            const float2 ta = Ttw[pp];
            const float2 tb = Ttw[25 + pp];
            if ((pp & 1) == 0) {
                AExx = fmaf(ta.x, s.x, AExx);
                AEyy = fmaf(ta.y, s.y, AEyy);
                AExy = fmaf(ta.x, s.y, AExy);
                AEyx = fmaf(ta.y, s.x, AEyx);
                BExx = fmaf(tb.x, s.x, BExx);
                BEyy = fmaf(tb.y, s.y, BEyy);
                BExy = fmaf(tb.x, s.y, BExy);
                BEyx = fmaf(tb.y, s.x, BEyx);
            } else {
                AOxx = fmaf(ta.x, s.x, AOxx);
                AOyy = fmaf(ta.y, s.y, AOyy);
                AOxy = fmaf(ta.x, s.y, AOxy);
                AOyx = fmaf(ta.y, s.x, AOyx);
                BOxx = fmaf(tb.x, s.x, BOxx);
                BOyy = fmaf(tb.y, s.y, BOyy);
                BOxy = fmaf(tb.x, s.y, BOxy);
                BOyx = fmaf(tb.y, s.x, BOyx);
            }
        }
        stageF[tid] = make_float2((AExx + AOxx) - (AEyy + AOyy),
                                  (AExy + AOxy) + (AEyx + AOyx));
        stageF[256 + tid] = make_float2((AExx - AOxx) + (AEyy - AOyy),
                                        (AExy - AOxy) - (AEyx - AOyx));
        stageF[512 + tid] = make_float2((BExx + BOxx) - (BEyy + BOyy),
                                        (BExy + BOxy) + (BEyx + BOyx));
        stageF[768 + tid] = make_float2((BExx - BOxx) + (BEyy - BOyy),
                                        (BExy - BOxy) - (BEyx - BOyx));
    }
    __syncthreads();  // B1: stage + tw visible

    const int p = (rs < 2) ? pa : pb;
    const int sb = rs & 2;
    const int u = ((rs & 1) == 0) ? p : (128 - p);   // 0..128
    const int um = u & 127;
    const int msel = (um == p) ? 0 : 1;
    const int mi = sb | msel;
    const int oi = sb | (1 - msel);

    const float ci = tw[um].x, si = -tw[um].y;
    const float b4 = 4.f / (1.f + __expf(9.f - alpha[img & 63])) + 4e-3f;  // 4b
    const float scale = 1.f / 65536.f;
    const float2 Di0 = make_float2(1.f + ci, si);
    const float2 Di1 = make_float2(1.f - ci, -si);
    const float2 Du = (u < 128) ? Di0 : Di1;
    float2 X0, X1, X2, X3;  // FX at cols q, q+64, q+128, q+192
#pragma unroll
    for (int h = 0; h < 2; ++h) {
        const int t = q + 64 * h;        // 0..127
        float2 f00 = stageF[mi * 256 + t];
        float2 f01 = stageF[mi * 256 + t + 128];
        float2 f10, f11;
        if (um == 0) {
            f10 = stageF[oi * 256 + t];
            f11 = stageF[oi * 256 + t + 128];
        } else {
            f10 = conjf2(stageF[oi * 256 + ((256 - t) & 255)]);
            f11 = conjf2(stageF[oi * 256 + 128 - t]);
        }
        // Fx stored cols 0..64; mirror t>64: conj(Fx[(128-um)%128][128-t])
        const bool mir = (t > 64);
        const int rr = mir ? ((128 - um) & 127) : um;
        const int cc = mir ? (128 - t) : t;
        float2 fx = Fx[(size_t)img * 16384 + rr * 128 + cc];
        if (mir) fx.y = -fx.y;
        const float cj = tw[t].x, sj = -tw[t].y;
        float2 Dj0 = make_float2(1.f + cj, sj);
        float2 Dj1 = make_float2(1.f - cj, -sj);
        // S1' = 4*S1, S2' = 4*S2; mm = (4 - S1')/(S2' + 4b)  (R16 algebra)
        float2 A = cadd(cmul(f00, Dj0), cmul(f01, Dj1));
        float2 Bt = cadd(cmul(f10, Dj0), cmul(f11, Dj1));
        float2 S1 = cadd(cmul(A, Di0), cmul(Bt, Di1));
        float S2 = f00.x * f00.x + f00.y * f00.y + f01.x * f01.x + f01.y * f01.y +
                   f10.x * f10.x + f10.y * f10.y + f11.x * f11.x + f11.y * f11.y;
        float inv = 1.f / (S2 + b4);
        float2 mm = make_float2((4.f - S1.x) * inv, (-S1.y) * inv);
        float2 c0v = (u < 128) ? f00 : f10;
        float2 c1v = (u < 128) ? f01 : f11;
        float2 t0 = cadd(cmul(conjf2(c0v), mm), cmul(Du, Dj0));
        float2 t1 = cadd(cmul(conjf2(c1v), mm), cmul(Du, Dj1));
        float2 FX0 = cmul(fx, t0);
        float2 FX1 = cmul(fx, t1);
        FX0.x *= scale; FX0.y *= scale;
        FX1.x *= scale; FX1.y *= scale;
        if (h == 0) { X0 = FX0; X2 = FX1; } else { X1 = FX0; X3 = FX1; }
    }

    // FFT stage m=1 in regs (jm=q, k=0): outputs at 4q..4q+3 -> 2x b128.
    {
        float2 s02 = cadd(X0, X2), d02 = csub(X0, X2);
        float2 s13 = cadd(X1, X3), d13 = csub(X1, X3);
        float2 b0 = cadd(s02, s13), b2v = csub(s02, s13);
        float2 b1 = make_float2(d02.x - d13.y, d02.y + d13.x);
        float2 b3 = make_float2(d02.x + d13.y, d02.y - d13.x);
        float2 c1 = cmul(tw[q], b1);
        float2 c2 = cmul(tw[2 * q], b2v);
        float2 c3 = cmul(tw[3 * q], b3);
        float4* dst4 = reinterpret_cast<float4*>(&sm_buf0[rs * 288 + PHI16(4 * q)]);
        dst4[0] = make_float4(b0.x, b0.y, c1.x, c1.y);
        dst4[1] = make_float4(c2.x, c2.y, c3.x, c3.y);
    }
    __syncthreads();  // B2: all stage (buf1) reads done before m=4 writes buf1

    // stage m=4: buf0 -> buf1 (wave-local)
    {
        const int k4 = q & 3, jm = q - k4;
        float2 a0 = sm_buf0[rs * 288 + PHI16(q)];
        float2 a1 = sm_buf0[rs * 288 + PHI16(q + 64)];
        float2 a2 = sm_buf0[rs * 288 + PHI16(q + 128)];
        float2 a3 = sm_buf0[rs * 288 + PHI16(q + 192)];
        float2 s02 = cadd(a0, a2), d02 = csub(a0, a2);
        float2 s13 = cadd(a1, a3), d13 = csub(a1, a3);
        float2 b0 = cadd(s02, s13), b2v = csub(s02, s13);
        float2 b1 = make_float2(d02.x - d13.y, d02.y + d13.x);
        float2 b3 = make_float2(d02.x + d13.y, d02.y - d13.x);
        const int o = 4 * jm + k4;
        sm_buf1[rs * 288 + PHI16(o)] = b0;
        sm_buf1[rs * 288 + PHI16(o + 4)] = cmul(tw[jm], b1);
        sm_buf1[rs * 288 + PHI16(o + 8)] = cmul(tw[2 * jm], b2v);
        sm_buf1[rs * 288 + PHI16(o + 12)] = cmul(tw[3 * jm], b3);
    }
    // stage m=16: buf1 -> buf0 (wave-local, in-order DS)
    {
        const int k16 = q & 15, jm = q - k16;
        float2 a0 = sm_buf1[rs * 288 + PHI16(q)];
        float2 a1 = sm_buf1[rs * 288 + PHI16(q + 64)];
        float2 a2 = sm_buf1[rs * 288 + PHI16(q + 128)];
        float2 a3 = sm_buf1[rs * 288 + PHI16(q + 192)];
        float2 s02 = cadd(a0, a2), d02 = csub(a0, a2);
        float2 s13 = cadd(a1, a3), d13 = csub(a1, a3);
        float2 b0 = cadd(s02, s13), b2v = csub(s02, s13);
        float2 b1 = make_float2(d02.x - d13.y, d02.y + d13.x);
        float2 b3 = make_float2(d02.x + d13.y, d02.y - d13.x);
        const int o = 4 * jm + k16;
        sm_buf0[rs * 288 + PHI16(o)] = b0;
        sm_buf0[rs * 288 + PHI16(o + 16)] = cmul(tw[jm], b1);
        sm_buf0[rs * 288 + PHI16(o + 32)] = cmul(tw[2 * jm], b2v);
        sm_buf0[rs * 288 + PHI16(o + 48)] = cmul(tw[3 * jm], b3);
    }
    // stage m=64 (jm=0, w=1) in regs: outputs at {q, q+64, q+128, q+192}.
    float2 Y0, Y1, Y2, Y3;
    {
        float2 a0 = sm_buf0[rs * 288 + PHI16(q)];
        float2 a1 = sm_buf0[rs * 288 + PHI16(q + 64)];
        float2 a2 = sm_buf0[rs * 288 + PHI16(q + 128)];
        float2 a3 = sm_buf0[rs * 288 + PHI16(q + 192)];
        float2 s02 = cadd(a0, a2), d02 = csub(a0, a2);
        float2 s13 = cadd(a1, a3), d13 = csub(a1, a3);
        Y0 = cadd(s02, s13);
        Y1 = make_float2(d02.x - d13.y, d02.y + d13.x);
        Y2 = csub(s02, s13);
        Y3 = make_float2(d02.x + d13.y, d02.y - d13.x);
    }
    // partner exchange for the fold (buf1 rs-region free after m=16 reads)
    sm_buf1[rs * 288 + PHI16(q)] = Y0;
    sm_buf1[rs * 288 + PHI16(q + 64)] = Y1;
    sm_buf1[rs * 288 + PHI16(q + 128)] = Y2;
    sm_buf1[rs * 288 + PHI16(q + 192)] = Y3;
    __syncthreads();  // B3: cross-wave fold reads rs^1

    // Hermitian fold: Zf[u0] = e + i*w.o, own values in regs, partner via LDS.
    const int u0 = u;
    bool dowrite = ((rs & 1) == 0) ? true : (p > 0 && p < 64);
    if (pb == pa && rs >= 2) dowrite = false;  // last-block dedup
    if (dowrite) {
        const float2 w = tw[u0];
        float2* zb = Zf + (size_t)img * 32768 + (size_t)u0 * 256;
        float2 own[4] = {Y0, Y1, Y2, Y3};
#pragma unroll
        for (int hh = 0; hh < 4; ++hh) {
            const int jj = q + 64 * hh;
            float2 su = own[hh];
            float2 s2 = sm_buf1[(rs ^ 1) * 288 + PHI16(jj)];
            float2 e = make_float2(su.x + s2.x, su.y - s2.y);   // su + conj(s2)
            float2 o_ = make_float2(su.x - s2.x, su.y + s2.y);  // su - conj(s2)
            float2 wo = cmul(w, o_);
            zb[jj] = make_float2(e.x - wo.y, e.y + wo.x);       // e + i*wo
        }
    }
}

// K7: pure C2R column IFFT, 32 cols/block, 512 threads, in-place (R18).
__global__ __launch_bounds__(512) void k7_c2r(const float2* __restrict__ Zf,
                                              float* __restrict__ out) {
    __shared__ float2 buf[32][131];
    __shared__ float2 tw[96];  // e^{+i pi k/64}
    const int tid = threadIdx.x;
    const int img = blockIdx.x >> 3;
    const int c0 = (blockIdx.x & 7) * 32;
    for (int i = tid; i < 96; i += 512) {
        float s, c;
        __sincosf((float)M_PI * (float)i / 64.f, &s, &c);
        tw[i] = make_float2(c, s);
    }
    const float2* zb = Zf + (size_t)img * 32768 + c0;
    for (int it = 0; it < 8; ++it) {
        int idx = it * 512 + tid;
        int rr = idx >> 5, cc = idx & 31;
        buf[cc][rr] = zb[rr * 256 + cc];
    }
    __syncthreads();
    fft4_cols_inplace<1, 32>(buf, tw);
    __syncthreads();
    float* ob = out + (size_t)img * 65536 + c0;
    for (int it = 0; it < 8; ++it) {
        int idx = it * 512 + tid;
        int n = idx >> 5, c = idx & 31;
        float2 y = buf[c][n];
        ob[(2 * n) * 256 + c] = y.x;
        ob[(2 * n + 1) * 256 + c] = y.y;
    }
}

extern "C" void kernel_launch(void* const* d_in, const int* in_sizes, int n_in,
                              void* d_out, int out_size, void* d_ws, size_t ws_size,
                              hipStream_t stream) {
    const float* x = (const float*)d_in[0];      // (4,64,128,128)
    const float* k = (const float*)d_in[1];      // (4,64,25,25)
    const float* alpha = (const float*)d_in[2];  // (1,64,1,1)
    float* out = (float*)d_out;                  // (4,64,256,256)

    float2* Fx = (float2*)d_ws;           // 256*16384   = 32 MB (cols 0..64 live)
    float2* Zf = Fx + 256 * 16384;        // 256*128*256 = 64 MB (folded)
    float2* FBtmp = Zf + 256 * 32768;     // 256*25*256  = 13.1 MB

    hipLaunchKernelGGL(k13, dim3(4096 + 256 * 7), dim3(256), 0, stream, x, k, Fx, FBtmp);
    hipLaunchKernelGGL(k2_fft_cols_x, dim3(256 * 5), dim3(256), 0, stream, Fx);
    hipLaunchKernelGGL(k6_fused, dim3(256 * 33), dim3(256), 0, stream, FBtmp, Fx, alpha, Zf);
    hipLaunchKernelGGL(k7_c2r, dim3(256 * 8), dim3(512), 0, stream, Zf, out);
}